// Round 1
// baseline (406.289 us; speedup 1.0000x reference)
//
#include <hip/hip_runtime.h>

// 1-D multi-resolution linear interp, 6 levels (sizes 8..256, 8 channels),
// N=2M points -> (N, 48) f32.  Write-bound: ~384 MB out, ~8 MB t in.
//
// R4 = R3 with the non-temporal store replaced by a PLAIN store.
// Rationale: rocprof shows the poison fill (plain stores) sustaining
// 6.4 TB/s while our NT-store kernel runs at ~2.45 TB/s effective.
// NT bypasses L2 write-combining; 16B-granular NT writes cost ~2x on the
// HBM write path. Plain stores let L2 assemble full 64B lines (each wave
// store instruction covers 1 KB contiguous), matching the fill kernel's
// write path. Output is never re-read, but L2 pollution is harmless here.
//
// Everything else identical to R3:
//  - 4096 persistent-ish blocks, grid-stride over output float4 indices
//  - volumes packed once per block into LDS, single __syncthreads
//  - t direct from global (12-way reuse via L1)

typedef float fx4 __attribute__((ext_vector_type(4)));

constexpr int NLEV = 6;
constexpr int CCH = 8;                      // channels
constexpr int ROWS_TOTAL = 504;             // 8+16+32+64+128+256
constexpr int BLK = 256;
constexpr int F4_PER_ROW = 12;              // 48 floats / 4

__global__ __launch_bounds__(BLK) void interp_multires_kernel(
    const float* __restrict__ t,
    const float* __restrict__ v0, const float* __restrict__ v1,
    const float* __restrict__ v2, const float* __restrict__ v3,
    const float* __restrict__ v4, const float* __restrict__ v5,
    float* __restrict__ out, int n)
{
    __shared__ __align__(16) float vol_lds[ROWS_TOTAL * CCH];  // 16128 B

    const int tid = threadIdx.x;

    // ---- stage all volumes into LDS once per block ----
    const float* vps[NLEV] = {v0, v1, v2, v3, v4, v5};
#pragma unroll
    for (int l = 0; l < NLEV; ++l) {
        const int sz = 8 << l;
        const int offf = (sz - 8) * CCH;
        const int n4 = sz * CCH / 4;
        fx4* dst = (fx4*)(vol_lds + offf);
        const fx4* src = (const fx4*)vps[l];
        for (int i = tid; i < n4; i += BLK) dst[i] = src[i];
    }
    __syncthreads();

    const int total4 = n * F4_PER_ROW;       // 24M, fits int32
    const int stride = gridDim.x * BLK;
    fx4* __restrict__ out4 = (fx4*)out;

    for (int g = blockIdx.x * BLK + tid; g < total4; g += stride) {
        const int row = g / F4_PER_ROW;       // magic-mul div
        const int q   = g - row * F4_PER_ROW; // 0..11
        const int lvl = q >> 1;
        const int cb  = (q & 1) * 4;          // channel base 0 or 4
        const int size = 8 << lvl;

        const float tc  = fminf(fmaxf(t[row], 0.0f), 1.0f);
        const float pos = tc * (float)(size - 1);
        int i0 = (int)floorf(pos);
        i0 = min(max(i0, 0), size - 2);
        const float w  = pos - (float)i0;
        const float om = 1.0f - w;

        const float* p = vol_lds + ((size - 8) + i0) * CCH + cb;
        const fx4 a = *(const fx4*)p;
        const fx4 b = *(const fx4*)(p + CCH);

        const fx4 r = a * om + b * w;
        out4[g] = r;                           // plain store: L2 write-combine
    }
}

extern "C" void kernel_launch(void* const* d_in, const int* in_sizes, int n_in,
                              void* d_out, int out_size, void* d_ws, size_t ws_size,
                              hipStream_t stream) {
    const float* t  = (const float*)d_in[0];
    const float* v0 = (const float*)d_in[1];
    const float* v1 = (const float*)d_in[2];
    const float* v2 = (const float*)d_in[3];
    const float* v3 = (const float*)d_in[4];
    const float* v4 = (const float*)d_in[5];
    const float* v5 = (const float*)d_in[6];
    float* out = (float*)d_out;

    const int n = in_sizes[0];                    // N (t is (N,1))
    const int total4 = n * F4_PER_ROW;
    int grid = 4096;                              // persistent-ish, ~23 iters/thread
    const int max_grid = (total4 + BLK - 1) / BLK;
    if (grid > max_grid) grid = max_grid;
    interp_multires_kernel<<<grid, BLK, 0, stream>>>(t, v0, v1, v2, v3, v4, v5,
                                                     out, n);
}

// Round 2
// 405.990 us; speedup vs baseline: 1.0007x; 1.0007x over previous
//
#include <hip/hip_runtime.h>

// 1-D multi-resolution linear interp, 6 levels (sizes 8..256, 8 channels),
// N=2M points -> (N, 48) f32.  Write-bound: ~384 MB out, ~8 MB t in.
//
// R5 = R4 + depth-2 software prefetch of t.
// Theory: kernel (~160us, 2.4 TB/s) is latency-bound on the fully-serial
// per-iter chain  t[row] -> i0 -> LDS addr -> ds_read -> fma -> store,
// where nearly every t line is an HBM-class miss (~900 cy) because each
// 64B line of t is touched by only ~1 block (8 incoherent L2s).
// 8 waves/SIMD x ~70 cy issue = ~560 cy of cover < ~1000 cy chain.
// Fix: issue t[row] two grid-stride iterations early; loads are older than
// stores in program order so the compiler waits with vmcnt(N>0), never on
// stores. Chain collapses to the ~140 cy LDS segment.
//
// Store is a plain dwordx4 (R4 showed NT vs plain is neutral).

typedef float fx4 __attribute__((ext_vector_type(4)));

constexpr int NLEV = 6;
constexpr int CCH = 8;                      // channels
constexpr int ROWS_TOTAL = 504;             // 8+16+32+64+128+256
constexpr int BLK = 256;
constexpr int F4_PER_ROW = 12;              // 48 floats / 4

__global__ __launch_bounds__(BLK) void interp_multires_kernel(
    const float* __restrict__ t,
    const float* __restrict__ v0, const float* __restrict__ v1,
    const float* __restrict__ v2, const float* __restrict__ v3,
    const float* __restrict__ v4, const float* __restrict__ v5,
    float* __restrict__ out, int n)
{
    __shared__ __align__(16) float vol_lds[ROWS_TOTAL * CCH];  // 16128 B

    const int tid = threadIdx.x;

    // ---- stage all volumes into LDS once per block ----
    const float* vps[NLEV] = {v0, v1, v2, v3, v4, v5};
#pragma unroll
    for (int l = 0; l < NLEV; ++l) {
        const int sz = 8 << l;
        const int offf = (sz - 8) * CCH;
        const int n4 = sz * CCH / 4;
        fx4* dst = (fx4*)(vol_lds + offf);
        const fx4* src = (const fx4*)vps[l];
        for (int i = tid; i < n4; i += BLK) dst[i] = src[i];
    }
    __syncthreads();

    const int total4 = n * F4_PER_ROW;       // 24M, fits int32
    const int stride = gridDim.x * BLK;
    fx4* __restrict__ out4 = (fx4*)out;

    int g0 = blockIdx.x * BLK + tid;
    if (g0 >= total4) return;                // after syncthreads: safe

    // ---- prologue: prime depth-2 t pipeline ----
    int   r0 = g0 / F4_PER_ROW;
    float t0 = t[r0];

    int   g1 = g0 + stride;
    bool  m1 = g1 < total4;
    int   r1 = 0;
    float t1 = 0.0f;
    if (m1) { r1 = g1 / F4_PER_ROW; t1 = t[r1]; }

    while (true) {
        // ---- prefetch t two iterations ahead (issued before any wait) ----
        const int  g2 = g1 + stride;
        const bool m2 = g2 < total4;          // m2 implies m1
        int   r2 = 0;
        float t2 = 0.0f;
        if (m2) { r2 = g2 / F4_PER_ROW; t2 = t[r2]; }

        // ---- process (g0, r0, t0) ----
        const int q   = g0 - r0 * F4_PER_ROW; // 0..11
        const int lvl = q >> 1;
        const int cb  = (q & 1) * 4;          // channel base 0 or 4
        const int size = 8 << lvl;

        const float tc  = fminf(fmaxf(t0, 0.0f), 1.0f);
        const float pos = tc * (float)(size - 1);
        int i0 = (int)floorf(pos);
        i0 = min(max(i0, 0), size - 2);
        const float w  = pos - (float)i0;
        const float om = 1.0f - w;

        const float* p = vol_lds + ((size - 8) + i0) * CCH + cb;
        const fx4 a = *(const fx4*)p;
        const fx4 b = *(const fx4*)(p + CCH);

        out4[g0] = a * om + b * w;

        if (!m1) break;
        g0 = g1; r0 = r1; t0 = t1;
        g1 = g2; m1 = m2; r1 = r2; t1 = t2;
    }
}

extern "C" void kernel_launch(void* const* d_in, const int* in_sizes, int n_in,
                              void* d_out, int out_size, void* d_ws, size_t ws_size,
                              hipStream_t stream) {
    const float* t  = (const float*)d_in[0];
    const float* v0 = (const float*)d_in[1];
    const float* v1 = (const float*)d_in[2];
    const float* v2 = (const float*)d_in[3];
    const float* v3 = (const float*)d_in[4];
    const float* v4 = (const float*)d_in[5];
    const float* v5 = (const float*)d_in[6];
    float* out = (float*)d_out;

    const int n = in_sizes[0];                    // N (t is (N,1))
    const int total4 = n * F4_PER_ROW;
    int grid = 4096;                              // persistent-ish, ~23 iters/thread
    const int max_grid = (total4 + BLK - 1) / BLK;
    if (grid > max_grid) grid = max_grid;
    interp_multires_kernel<<<grid, BLK, 0, stream>>>(t, v0, v1, v2, v3, v4, v5,
                                                     out, n);
}